// Round 5
// baseline (3870.048 us; speedup 1.0000x reference)
//
#include <hip/hip_runtime.h>
#include <cstdint>
#include <cstddef>

#define NN 8192
#define EE 524288
#define HH 128
#define BB 16
#define NHEADS 4

// GEMM tiling
#define BM 64
#define BN 128
#define BK 32

enum { X_PLAIN = 0, X_NODE = 1, X_EDGE = 2 };
enum { EPI_NONE = 0, EPI_RELU = 1, EPI_RESID = 2 };

// ---------------------------------------------------------------------------
// Generic fp32 tiled GEMM: out[M][Nout] = X[M][K] @ W[Nout][K]^T + bias
// X_NODE: col 128 = rho[row]   (K=129)
// X_EDGE: col 128 = rho[src[row]], 129 = rho[dst[row]], 130 = fk[row] (K=131)
// M assumed multiple of 64. grid.y tiles Nout in chunks of 128.
// ---------------------------------------------------------------------------
template<int XMODE, int EPI>
__launch_bounds__(256, 2)
__global__ void gemm_k(const float* __restrict__ X,
                       const float* __restrict__ W,
                       const float* __restrict__ bias,
                       float* __restrict__ out,
                       int M, int K, int ldo,
                       const float* __restrict__ resid,
                       const float* __restrict__ rho,
                       const float* __restrict__ fk,
                       const int* __restrict__ esrc,
                       const int* __restrict__ edst)
{
    __shared__ float Xs[BM][36];    // 36: 16B-aligned row stride for b128 reads
    __shared__ float Ws[BK][132];   // [kk][col], 132: aligned + low conflict
    const int tid = threadIdx.x;
    const int m0  = blockIdx.x * BM;
    const int c0  = blockIdx.y * BN;
    const int tr  = tid >> 5;       // 8 row-groups of 8 rows
    const int tc  = tid & 31;       // 32 col-groups of 4 cols
    float acc[8][4] = {};
    const int nk = (K + BK - 1) / BK;
    for (int kt = 0; kt < nk; ++kt) {
        const int k0 = kt * BK;
        #pragma unroll
        for (int i = 0; i < 8; ++i) {           // 64x32 X tile
            int idx = tid + i * 256;
            int r = idx >> 5, kk = idx & 31;
            int gr = m0 + r, gk = k0 + kk;
            float v = 0.f;
            if (XMODE == X_PLAIN) {
                if (gk < K) v = X[(size_t)gr * K + gk];
            } else if (XMODE == X_NODE) {
                if (gk < 128) v = X[(size_t)gr * 128 + gk];
                else if (gk == 128) v = rho[gr];
            } else { // X_EDGE
                if (gk < 128) v = X[(size_t)gr * 128 + gk];
                else if (gk == 128) v = rho[esrc[gr]];
                else if (gk == 129) v = rho[edst[gr]];
                else if (gk == 130) v = fk[gr];
            }
            Xs[r][kk] = v;
        }
        #pragma unroll
        for (int i = 0; i < 16; ++i) {          // 128x32 W tile (transposed)
            int idx = tid + i * 256;
            int col = idx >> 5, kk = idx & 31;
            int gk = k0 + kk;
            float w = 0.f;
            if (gk < K) w = W[(size_t)(c0 + col) * K + gk];
            Ws[kk][col] = w;
        }
        __syncthreads();
        #pragma unroll
        for (int k4 = 0; k4 < BK / 4; ++k4) {
            float4 xr[8];
            #pragma unroll
            for (int i = 0; i < 8; ++i)
                xr[i] = *(const float4*)&Xs[tr * 8 + i][k4 * 4];
            #pragma unroll
            for (int u = 0; u < 4; ++u) {
                float4 wv = *(const float4*)&Ws[k4 * 4 + u][tc * 4];
                #pragma unroll
                for (int i = 0; i < 8; ++i) {
                    float xv = ((const float*)&xr[i])[u];
                    acc[i][0] += xv * wv.x;
                    acc[i][1] += xv * wv.y;
                    acc[i][2] += xv * wv.z;
                    acc[i][3] += xv * wv.w;
                }
            }
        }
        __syncthreads();
    }
    const int gc = c0 + tc * 4;
    float4 bv = *(const float4*)&bias[gc];
    #pragma unroll
    for (int i = 0; i < 8; ++i) {
        int gr = m0 + tr * 8 + i;
        float4 v;
        v.x = acc[i][0] + bv.x; v.y = acc[i][1] + bv.y;
        v.z = acc[i][2] + bv.z; v.w = acc[i][3] + bv.w;
        if (EPI == EPI_RELU) {
            v.x = fmaxf(v.x, 0.f); v.y = fmaxf(v.y, 0.f);
            v.z = fmaxf(v.z, 0.f); v.w = fmaxf(v.w, 0.f);
        }
        if (EPI == EPI_RESID) {
            float4 rr = *(const float4*)&resid[(size_t)gr * ldo + gc];
            v.x += rr.x; v.y += rr.y; v.z += rr.z; v.w += rr.w;
        }
        *(float4*)&out[(size_t)gr * ldo + gc] = v;
    }
}

// ---------------------------------------------------------------------------
// Ce GEMM + e_ij = Dx[dst]+Ex[src]+Ce, sigma=sigmoid, atomic segment sums
// ---------------------------------------------------------------------------
__launch_bounds__(256, 2)
__global__ void ce_eij_k(const float* __restrict__ he,
                         const float* __restrict__ W,
                         const float* __restrict__ bias,
                         const float* __restrict__ Dx,
                         const float* __restrict__ Exm,
                         const float* __restrict__ Bx,
                         const int* __restrict__ esrc,
                         const int* __restrict__ edst,
                         float* __restrict__ e_ij,
                         float* __restrict__ agg_num,
                         float* __restrict__ agg_den)
{
    __shared__ float Xs[BM][36];
    __shared__ float Ws[BK][132];
    const int tid = threadIdx.x;
    const int m0  = blockIdx.x * BM;
    const int tr  = tid >> 5;
    const int tc  = tid & 31;
    float acc[8][4] = {};
    for (int kt = 0; kt < 4; ++kt) {        // K = 128
        const int k0 = kt * BK;
        #pragma unroll
        for (int i = 0; i < 8; ++i) {
            int idx = tid + i * 256;
            int r = idx >> 5, kk = idx & 31;
            Xs[r][kk] = he[(size_t)(m0 + r) * 128 + k0 + kk];
        }
        #pragma unroll
        for (int i = 0; i < 16; ++i) {
            int idx = tid + i * 256;
            int col = idx >> 5, kk = idx & 31;
            Ws[kk][col] = W[(size_t)col * 128 + k0 + kk];
        }
        __syncthreads();
        #pragma unroll
        for (int k4 = 0; k4 < BK / 4; ++k4) {
            float4 xr[8];
            #pragma unroll
            for (int i = 0; i < 8; ++i)
                xr[i] = *(const float4*)&Xs[tr * 8 + i][k4 * 4];
            #pragma unroll
            for (int u = 0; u < 4; ++u) {
                float4 wv = *(const float4*)&Ws[k4 * 4 + u][tc * 4];
                #pragma unroll
                for (int i = 0; i < 8; ++i) {
                    float xv = ((const float*)&xr[i])[u];
                    acc[i][0] += xv * wv.x;
                    acc[i][1] += xv * wv.y;
                    acc[i][2] += xv * wv.z;
                    acc[i][3] += xv * wv.w;
                }
            }
        }
        __syncthreads();
    }
    const int gc = tc * 4;
    float4 bv = *(const float4*)&bias[gc];
    #pragma unroll
    for (int i = 0; i < 8; ++i) {
        int gr = m0 + tr * 8 + i;
        int s = esrc[gr], d = edst[gr];
        float4 dv  = *(const float4*)&Dx [(size_t)d * 128 + gc];
        float4 ev  = *(const float4*)&Exm[(size_t)s * 128 + gc];
        float4 bxv = *(const float4*)&Bx [(size_t)s * 128 + gc];
        float4 e4;
        e4.x = acc[i][0] + bv.x + dv.x + ev.x;
        e4.y = acc[i][1] + bv.y + dv.y + ev.y;
        e4.z = acc[i][2] + bv.z + dv.z + ev.z;
        e4.w = acc[i][3] + bv.w + dv.w + ev.w;
        *(float4*)&e_ij[(size_t)gr * 128 + gc] = e4;
        float sg;
        size_t nb = (size_t)d * 128 + gc;
        sg = 1.f / (1.f + __expf(-e4.x));
        atomicAdd(&agg_num[nb + 0], sg * bxv.x); atomicAdd(&agg_den[nb + 0], sg);
        sg = 1.f / (1.f + __expf(-e4.y));
        atomicAdd(&agg_num[nb + 1], sg * bxv.y); atomicAdd(&agg_den[nb + 1], sg);
        sg = 1.f / (1.f + __expf(-e4.z));
        atomicAdd(&agg_num[nb + 2], sg * bxv.z); atomicAdd(&agg_den[nb + 2], sg);
        sg = 1.f / (1.f + __expf(-e4.w));
        atomicAdd(&agg_num[nb + 3], sg * bxv.w); atomicAdd(&agg_den[nb + 3], sg);
    }
}

// ---------------------------------------------------------------------------
// Per-channel sum/sumsq over rows (for batchnorm stats)
// ---------------------------------------------------------------------------
__global__ void bnstats_k(const float* __restrict__ x, int M,
                          float* __restrict__ sum, float* __restrict__ sumsq)
{
    const int col  = threadIdx.x & 127;
    const int half = threadIdx.x >> 7;
    const int stride = 2 * gridDim.x;
    float s = 0.f, ss = 0.f;
    for (int r = blockIdx.x * 2 + half; r < M; r += stride) {
        float v = x[(size_t)r * 128 + col];
        s += v; ss += v * v;
    }
    __shared__ float Ss[2][128], SSs[2][128];
    Ss[half][col] = s; SSs[half][col] = ss;
    __syncthreads();
    if (half == 0) {
        atomicAdd(&sum[col],   Ss[0][col] + Ss[1][col]);
        atomicAdd(&sumsq[col], SSs[0][col] + SSs[1][col]);
    }
}

__global__ void bnfinal_k(const float* esum, const float* esumsq,
                          const float* xsum, const float* xsumsq,
                          const float* eg, const float* eb,
                          const float* xg, const float* xb,
                          float* esc, float* esh, float* xsc, float* xsh)
{
    int c = threadIdx.x;
    float me = esum[c] * (1.f / EE);
    float ve = esumsq[c] * (1.f / EE) - me * me;
    float se = eg[c] * rsqrtf(ve + 1e-5f);
    esc[c] = se; esh[c] = eb[c] - me * se;
    float mx = xsum[c] * (1.f / NN);
    float vx = xsumsq[c] * (1.f / NN) - mx * mx;
    float sx = xg[c] * rsqrtf(vx + 1e-5f);
    xsc[c] = sx; xsh[c] = xb[c] - mx * sx;
}

__global__ void xcombine_k(const float* __restrict__ Ax,
                           const float* __restrict__ num,
                           const float* __restrict__ den,
                           float* __restrict__ xpre)
{
    int i = blockIdx.x * 1024 + threadIdx.x * 4;
    float4 a = *(const float4*)&Ax[i];
    float4 n = *(const float4*)&num[i];
    float4 d = *(const float4*)&den[i];
    float4 o;
    o.x = a.x + n.x / (d.x + 1e-6f);
    o.y = a.y + n.y / (d.y + 1e-6f);
    o.z = a.z + n.z / (d.z + 1e-6f);
    o.w = a.w + n.w / (d.w + 1e-6f);
    *(float4*)&xpre[i] = o;
}

__global__ void xpost_k(const float* __restrict__ xpre,
                        const float* __restrict__ hv,
                        const float* __restrict__ xsc,
                        const float* __restrict__ xsh,
                        float* __restrict__ xfin)
{
    int i = blockIdx.x * 1024 + threadIdx.x * 4;
    int c = i & 127;
    float4 v  = *(const float4*)&xpre[i];
    float4 s4 = *(const float4*)&xsc[c];
    float4 h4 = *(const float4*)&xsh[c];
    float4 r4 = *(const float4*)&hv[i];
    float4 o;
    o.x = fmaxf(v.x * s4.x + h4.x, 0.f) + r4.x;
    o.y = fmaxf(v.y * s4.y + h4.y, 0.f) + r4.y;
    o.z = fmaxf(v.z * s4.z + h4.z, 0.f) + r4.z;
    o.w = fmaxf(v.w * s4.w + h4.w, 0.f) + r4.w;
    *(float4*)&xfin[i] = o;
}

// ---------------------------------------------------------------------------
// e = relu(bn(e_ij)) + he (he pre-stored in e_out) ; delta readout fused
// ---------------------------------------------------------------------------
__launch_bounds__(256, 2)
__global__ void epost_delta_k(const float* __restrict__ e_ij,
                              float* __restrict__ e_out,
                              const float* __restrict__ esc,
                              const float* __restrict__ esh,
                              const float* __restrict__ w1,
                              const float* __restrict__ b1,
                              const float* __restrict__ w2,
                              const float* __restrict__ b2,
                              float* __restrict__ delta)
{
    __shared__ float Es[BM][132];
    __shared__ float Ws[BK][132];
    __shared__ float red[BM][33];
    __shared__ float w2s[128], b1s[128];
    const int tid = threadIdx.x;
    const int m0  = blockIdx.x * BM;
    const int tr  = tid >> 5;
    const int tc  = tid & 31;
    const int gc  = tc * 4;
    if (tid < 128) { w2s[tid] = w2[tid]; b1s[tid] = b1[tid]; }
    float4 sc4 = *(const float4*)&esc[gc];
    float4 sh4 = *(const float4*)&esh[gc];
    #pragma unroll
    for (int i = 0; i < 8; ++i) {
        int gr = m0 + tr * 8 + i;
        float4 ij  = *(const float4*)&e_ij [(size_t)gr * 128 + gc];
        float4 hev = *(const float4*)&e_out[(size_t)gr * 128 + gc];
        float4 ev;
        ev.x = fmaxf(ij.x * sc4.x + sh4.x, 0.f) + hev.x;
        ev.y = fmaxf(ij.y * sc4.y + sh4.y, 0.f) + hev.y;
        ev.z = fmaxf(ij.z * sc4.z + sh4.z, 0.f) + hev.z;
        ev.w = fmaxf(ij.w * sc4.w + sh4.w, 0.f) + hev.w;
        *(float4*)&e_out[(size_t)gr * 128 + gc] = ev;
        *(float4*)&Es[tr * 8 + i][gc] = ev;
    }
    __syncthreads();
    float acc[8][4] = {};
    for (int kt = 0; kt < 4; ++kt) {
        const int k0 = kt * 32;
        if (kt > 0) __syncthreads();
        #pragma unroll
        for (int i = 0; i < 16; ++i) {
            int idx = tid + i * 256;
            int col = idx >> 5, kk = idx & 31;
            Ws[kk][col] = w1[(size_t)col * 128 + k0 + kk];
        }
        __syncthreads();
        #pragma unroll
        for (int k4 = 0; k4 < 8; ++k4) {
            float4 xr[8];
            #pragma unroll
            for (int i = 0; i < 8; ++i)
                xr[i] = *(const float4*)&Es[tr * 8 + i][k0 + k4 * 4];
            #pragma unroll
            for (int u = 0; u < 4; ++u) {
                float4 wv = *(const float4*)&Ws[k4 * 4 + u][tc * 4];
                #pragma unroll
                for (int i = 0; i < 8; ++i) {
                    float xv = ((const float*)&xr[i])[u];
                    acc[i][0] += xv * wv.x;
                    acc[i][1] += xv * wv.y;
                    acc[i][2] += xv * wv.z;
                    acc[i][3] += xv * wv.w;
                }
            }
        }
    }
    __syncthreads();
    #pragma unroll
    for (int i = 0; i < 8; ++i) {
        float p = 0.f;
        #pragma unroll
        for (int j = 0; j < 4; ++j) {
            float t = fmaxf(acc[i][j] + b1s[gc + j], 0.f);
            p += t * w2s[gc + j];
        }
        red[tr * 8 + i][tc] = p;
    }
    __syncthreads();
    if (tid < 64) {
        float s = 0.f;
        #pragma unroll
        for (int c = 0; c < 32; ++c) s += red[tid][c];
        delta[m0 + tid] = s + b2[0];
    }
}

// ---------------------------------------------------------------------------
// batch_vec -> starts/counts (batch_vec sorted)
// ---------------------------------------------------------------------------
__global__ void meta_k(const int* __restrict__ bvec, int* starts, int* counts)
{
    __shared__ int cnt[BB];
    if (threadIdx.x < BB) cnt[threadIdx.x] = 0;
    __syncthreads();
    for (int i = threadIdx.x; i < NN; i += 256) atomicAdd(&cnt[bvec[i]], 1);
    __syncthreads();
    if (threadIdx.x == 0) {
        int s = 0;
        for (int b = 0; b < BB; ++b) { starts[b] = s; counts[b] = cnt[b]; s += cnt[b]; }
    }
}

// ---------------------------------------------------------------------------
// Flash attention, per (graph, head, 32-query tile). hd=32, keys tiled by 64.
// qkv rows are only the valid (ragged) node rows; graph b = rows [st, st+cnt).
// ---------------------------------------------------------------------------
__launch_bounds__(256, 2)
__global__ void attn_k(const float* __restrict__ qkv,
                       const int* __restrict__ starts,
                       const int* __restrict__ counts,
                       float* __restrict__ ctx)
{
    const int b  = blockIdx.x;
    const int h  = blockIdx.y;
    const int qt = blockIdx.z;
    const int cnt = counts[b];
    const int st  = starts[b];
    const int q0  = qt * 32;
    if (q0 >= cnt) return;
    __shared__ float Ks[64][36];
    __shared__ float Vs[64][36];
    __shared__ float Ps[32][68];
    const int tid = threadIdx.x;
    const int qi  = tid >> 3;
    const int sub = tid & 7;
    const int qrow = q0 + qi;
    float4 qv[8];
    if (qrow < cnt) {
        const float* qp = &qkv[(size_t)(st + qrow) * 384 + h * 32];
        #pragma unroll
        for (int c4 = 0; c4 < 8; ++c4) qv[c4] = *(const float4*)&qp[c4 * 4];
    } else {
        #pragma unroll
        for (int c4 = 0; c4 < 8; ++c4) qv[c4] = make_float4(0.f, 0.f, 0.f, 0.f);
    }
    float m = -1e30f, l = 0.f;
    float a0 = 0.f, a1 = 0.f, a2 = 0.f, a3 = 0.f;
    const int nkt = (cnt + 63) >> 6;
    for (int kt = 0; kt < nkt; ++kt) {
        const int kk0 = kt * 64;
        __syncthreads();
        #pragma unroll
        for (int i = 0; i < 8; ++i) {
            int idx = tid + i * 256;
            int r = idx >> 5, c = idx & 31;
            int kg = kk0 + r;
            float kvv = 0.f, vvv = 0.f;
            if (kg < cnt) {
                size_t base = (size_t)(st + kg) * 384 + h * 32;
                kvv = qkv[base + 128 + c];
                vvv = qkv[base + 256 + c];
            }
            Ks[r][c] = kvv;
            Vs[r][c] = vvv;
        }
        __syncthreads();
        float p[8];
        float tmax = -1e30f;
        #pragma unroll
        for (int j2 = 0; j2 < 8; ++j2) {
            int j = sub * 8 + j2;
            float s = 0.f;
            #pragma unroll
            for (int c4 = 0; c4 < 8; ++c4) {
                float4 kv4 = *(const float4*)&Ks[j][c4 * 4];
                s += qv[c4].x * kv4.x + qv[c4].y * kv4.y
                   + qv[c4].z * kv4.z + qv[c4].w * kv4.w;
            }
            s *= 0.17677669529663687f;     // 1/sqrt(32)
            if (kk0 + j >= cnt) s = -1e30f;
            p[j2] = s;
            tmax = fmaxf(tmax, s);
        }
        #pragma unroll
        for (int d = 1; d < 8; d <<= 1) tmax = fmaxf(tmax, __shfl_xor(tmax, d));
        const float mnew = fmaxf(m, tmax);
        const float corr = __expf(m - mnew);
        float tsum = 0.f;
        #pragma unroll
        for (int j2 = 0; j2 < 8; ++j2) {
            float pe = __expf(p[j2] - mnew);
            p[j2] = pe;
            tsum += pe;
        }
        #pragma unroll
        for (int d = 1; d < 8; d <<= 1) tsum += __shfl_xor(tsum, d);
        l = l * corr + tsum;
        m = mnew;
        a0 *= corr; a1 *= corr; a2 *= corr; a3 *= corr;
        #pragma unroll
        for (int j2 = 0; j2 < 8; ++j2) Ps[qi][sub * 8 + j2] = p[j2];
        __syncthreads();
        for (int j = 0; j < 64; ++j) {
            float pj = Ps[qi][j];
            float4 vv = *(const float4*)&Vs[j][sub * 4];
            a0 += pj * vv.x; a1 += pj * vv.y; a2 += pj * vv.z; a3 += pj * vv.w;
        }
    }
    if (qrow < cnt) {
        float inv = 1.f / l;
        float4 o = make_float4(a0 * inv, a1 * inv, a2 * inv, a3 * inv);
        *(float4*)&ctx[(size_t)(st + qrow) * 128 + h * 32 + sub * 4] = o;
    }
}

// ---------------------------------------------------------------------------
// LayerNorm over rows of 128 (eps 1e-5), one wave per row
// ---------------------------------------------------------------------------
__global__ void ln_k(const float* __restrict__ x,
                     const float* __restrict__ g,
                     const float* __restrict__ b,
                     float* __restrict__ out, int M)
{
    int row  = blockIdx.x * 4 + (threadIdx.x >> 6);
    int lane = threadIdx.x & 63;
    if (row >= M) return;
    float2 v = *(const float2*)&x[(size_t)row * 128 + lane * 2];
    float s  = v.x + v.y;
    float ss = v.x * v.x + v.y * v.y;
    #pragma unroll
    for (int d = 1; d < 64; d <<= 1) {
        s  += __shfl_xor(s, d);
        ss += __shfl_xor(ss, d);
    }
    float mean = s * (1.f / 128.f);
    float var  = ss * (1.f / 128.f) - mean * mean;
    float inv  = rsqrtf(var + 1e-5f);
    float2 o;
    o.x = (v.x - mean) * inv * g[lane * 2 + 0] + b[lane * 2 + 0];
    o.y = (v.y - mean) * inv * g[lane * 2 + 1] + b[lane * 2 + 1];
    *(float2*)&out[(size_t)row * 128 + lane * 2] = o;
}

extern "C" void kernel_launch(void* const* d_in, const int* in_sizes, int n_in,
                              void* d_out, int out_size, void* d_ws, size_t ws_size,
                              hipStream_t stream) {
    (void)in_sizes; (void)n_in; (void)out_size; (void)ws_size;
    const float* h_v   = (const float*)d_in[0];
    const float* h_e   = (const float*)d_in[1];
    const float* rho_v = (const float*)d_in[2];
    const float* f_k   = (const float*)d_in[3];
    const float* ei_w  = (const float*)d_in[4];
    const float* ei_b  = (const float*)d_in[5];
    const float* ni_w  = (const float*)d_in[6];
    const float* ni_b  = (const float*)d_in[7];
    const float* Aw = (const float*)d_in[8],  *Ab = (const float*)d_in[9];
    const float* Bw = (const float*)d_in[10], *Bb = (const float*)d_in[11];
    const float* Cw = (const float*)d_in[12], *Cb = (const float*)d_in[13];
    const float* Dw = (const float*)d_in[14], *Db = (const float*)d_in[15];
    const float* Ew = (const float*)d_in[16], *Eb = (const float*)d_in[17];
    const float* bnxg = (const float*)d_in[18], *bnxb = (const float*)d_in[19];
    const float* bneg = (const float*)d_in[20], *bneb = (const float*)d_in[21];
    const float* aiw = (const float*)d_in[22], *aib = (const float*)d_in[23];
    const float* aow = (const float*)d_in[24], *aob = (const float*)d_in[25];
    const float* ln1g = (const float*)d_in[26], *ln1b = (const float*)d_in[27];
    const float* ln2g = (const float*)d_in[28], *ln2b = (const float*)d_in[29];
    const float* f1w = (const float*)d_in[30], *f1b = (const float*)d_in[31];
    const float* f2w = (const float*)d_in[32], *f2b = (const float*)d_in[33];
    const float* row1 = (const float*)d_in[34], *rob1 = (const float*)d_in[35];
    const float* row2 = (const float*)d_in[36], *rob2 = (const float*)d_in[37];
    const int* eidx = (const int*)d_in[38];
    const int* bvec = (const int*)d_in[39];
    const int* esrc = eidx;
    const int* edst = eidx + EE;

    float* ws = (float*)d_ws;
    size_t o = 0;
    float* e_ij   = ws + o; o += (size_t)EE * HH;
    float* hv     = ws + o; o += (size_t)NN * HH;
    float* Ax     = ws + o; o += (size_t)NN * HH;
    float* Bx     = ws + o; o += (size_t)NN * HH;
    float* Dx     = ws + o; o += (size_t)NN * HH;
    float* Exm    = ws + o; o += (size_t)NN * HH;
    float* agg_nm = ws + o; o += (size_t)NN * HH;
    float* agg_dn = ws + o; o += (size_t)NN * HH;
    float* x_fin  = ws + o; o += (size_t)NN * HH;
    float* qkvb   = ws + o; o += (size_t)3 * NN * HH;
    float* ctx    = ws + o; o += (size_t)NN * HH;
    float* xd1    = ws + o; o += (size_t)NN * HH;
    float* esum   = ws + o; o += 128;
    float* esumsq = ws + o; o += 128;
    float* xsum   = ws + o; o += 128;
    float* xsumsq = ws + o; o += 128;
    float* esc    = ws + o; o += 128;
    float* esh    = ws + o; o += 128;
    float* xsc    = ws + o; o += 128;
    float* xsh    = ws + o; o += 128;
    int*   meta   = (int*)(ws + o); o += 32;
    // aliases (lifetimes verified disjoint):
    float* xpre = Ax;          // xcombine overwrites Ax in place
    float* f1   = Bx;          // spans Bx,Dx,Exm,agg_nm (N*512 floats)
    float* tmp1 = qkvb;        // post-attention residual buffer
    float* tmp2 = ctx;         // post-ffn residual buffer

    float* out_x     = (float*)d_out;
    float* he        = out_x + (size_t)NN * HH;       // e region doubles as he scratch
    float* out_delta = he + (size_t)EE * HH;

    hipMemsetAsync(agg_nm, 0, 2 * (size_t)NN * HH * sizeof(float), stream);
    hipMemsetAsync(esum, 0, 4 * 128 * sizeof(float), stream);

    dim3 blk(256);
    meta_k<<<1, blk, 0, stream>>>(bvec, meta, meta + BB);

    // hv = [h_v, rho_v] @ ni_w^T + ni_b
    gemm_k<X_NODE, EPI_NONE><<<dim3(NN / BM, 1), blk, 0, stream>>>(
        h_v, ni_w, ni_b, hv, NN, 129, 128, nullptr, rho_v, nullptr, nullptr, nullptr);
    // he = [h_e, rho[src], rho[dst], f_k] @ ei_w^T + ei_b  (into d_out e-region)
    gemm_k<X_EDGE, EPI_NONE><<<dim3(EE / BM, 1), blk, 0, stream>>>(
        h_e, ei_w, ei_b, he, EE, 131, 128, nullptr, rho_v, f_k, esrc, edst);
    // A/B/D/E projections of hv
    gemm_k<X_PLAIN, EPI_NONE><<<dim3(NN / BM, 1), blk, 0, stream>>>(
        hv, Aw, Ab, Ax, NN, 128, 128, nullptr, nullptr, nullptr, nullptr, nullptr);
    gemm_k<X_PLAIN, EPI_NONE><<<dim3(NN / BM, 1), blk, 0, stream>>>(
        hv, Bw, Bb, Bx, NN, 128, 128, nullptr, nullptr, nullptr, nullptr, nullptr);
    gemm_k<X_PLAIN, EPI_NONE><<<dim3(NN / BM, 1), blk, 0, stream>>>(
        hv, Dw, Db, Dx, NN, 128, 128, nullptr, nullptr, nullptr, nullptr, nullptr);
    gemm_k<X_PLAIN, EPI_NONE><<<dim3(NN / BM, 1), blk, 0, stream>>>(
        hv, Ew, Eb, Exm, NN, 128, 128, nullptr, nullptr, nullptr, nullptr, nullptr);
    // Ce + gather + sigmoid + segment sums
    ce_eij_k<<<dim3(EE / BM), blk, 0, stream>>>(
        he, Cw, Cb, Dx, Exm, Bx, esrc, edst, e_ij, agg_nm, agg_dn);
    // batchnorm stats
    bnstats_k<<<1024, blk, 0, stream>>>(e_ij, EE, esum, esumsq);
    xcombine_k<<<(NN * HH) / 1024, blk, 0, stream>>>(Ax, agg_nm, agg_dn, xpre);
    bnstats_k<<<64, blk, 0, stream>>>(xpre, NN, xsum, xsumsq);
    bnfinal_k<<<1, 128, 0, stream>>>(esum, esumsq, xsum, xsumsq,
                                     bneg, bneb, bnxg, bnxb, esc, esh, xsc, xsh);
    xpost_k<<<(NN * HH) / 1024, blk, 0, stream>>>(xpre, hv, xsc, xsh, x_fin);
    // e (+residual he) + fused delta readout
    epost_delta_k<<<dim3(EE / BM), blk, 0, stream>>>(
        e_ij, he, esc, esh, row1, rob1, row2, rob2, out_delta);
    // attention stream
    gemm_k<X_PLAIN, EPI_NONE><<<dim3(NN / BM, 3), blk, 0, stream>>>(
        x_fin, aiw, aib, qkvb, NN, 128, 384, nullptr, nullptr, nullptr, nullptr, nullptr);
    attn_k<<<dim3(BB, NHEADS, 32), blk, 0, stream>>>(qkvb, meta, meta + BB, ctx);
    gemm_k<X_PLAIN, EPI_RESID><<<dim3(NN / BM, 1), blk, 0, stream>>>(
        ctx, aow, aob, tmp1, NN, 128, 128, x_fin, nullptr, nullptr, nullptr, nullptr);
    ln_k<<<NN / 4, blk, 0, stream>>>(tmp1, ln1g, ln1b, xd1, NN);
    gemm_k<X_PLAIN, EPI_RELU><<<dim3(NN / BM, 4), blk, 0, stream>>>(
        xd1, f1w, f1b, f1, NN, 128, 512, nullptr, nullptr, nullptr, nullptr, nullptr);
    gemm_k<X_PLAIN, EPI_RESID><<<dim3(NN / BM, 1), blk, 0, stream>>>(
        f1, f2w, f2b, tmp2, NN, 512, 128, xd1, nullptr, nullptr, nullptr, nullptr);
    ln_k<<<NN / 4, blk, 0, stream>>>(tmp2, ln2g, ln2b, out_x, NN);
}

// Round 6
// 2427.077 us; speedup vs baseline: 1.5945x; 1.5945x over previous
//
#include <hip/hip_runtime.h>
#include <cstdint>
#include <cstddef>

#define NN 8192
#define EE 524288
#define HH 128
#define BB 16
#define NHEADS 4

// GEMM tiling
#define BM 64
#define BN 128
#define BK 32

enum { X_PLAIN = 0, X_NODE = 1, X_EDGE = 2 };
enum { EPI_NONE = 0, EPI_RELU = 1, EPI_RESID = 2 };

// ---------------------------------------------------------------------------
// Generic fp32 tiled GEMM: out[M][Nout] = X[M][K] @ W[Nout][K]^T + bias
// ---------------------------------------------------------------------------
template<int XMODE, int EPI>
__launch_bounds__(256, 2)
__global__ void gemm_k(const float* __restrict__ X,
                       const float* __restrict__ W,
                       const float* __restrict__ bias,
                       float* __restrict__ out,
                       int M, int K, int ldo,
                       const float* __restrict__ resid,
                       const float* __restrict__ rho,
                       const float* __restrict__ fk,
                       const int* __restrict__ esrc,
                       const int* __restrict__ edst)
{
    __shared__ float Xs[BM][36];
    __shared__ float Ws[BK][132];
    const int tid = threadIdx.x;
    const int m0  = blockIdx.x * BM;
    const int c0  = blockIdx.y * BN;
    const int tr  = tid >> 5;
    const int tc  = tid & 31;
    float acc[8][4] = {};
    const int nk = (K + BK - 1) / BK;
    for (int kt = 0; kt < nk; ++kt) {
        const int k0 = kt * BK;
        #pragma unroll
        for (int i = 0; i < 8; ++i) {
            int idx = tid + i * 256;
            int r = idx >> 5, kk = idx & 31;
            int gr = m0 + r, gk = k0 + kk;
            float v = 0.f;
            if (XMODE == X_PLAIN) {
                if (gk < K) v = X[(size_t)gr * K + gk];
            } else if (XMODE == X_NODE) {
                if (gk < 128) v = X[(size_t)gr * 128 + gk];
                else if (gk == 128) v = rho[gr];
            } else {
                if (gk < 128) v = X[(size_t)gr * 128 + gk];
                else if (gk == 128) v = rho[esrc[gr]];
                else if (gk == 129) v = rho[edst[gr]];
                else if (gk == 130) v = fk[gr];
            }
            Xs[r][kk] = v;
        }
        #pragma unroll
        for (int i = 0; i < 16; ++i) {
            int idx = tid + i * 256;
            int col = idx >> 5, kk = idx & 31;
            int gk = k0 + kk;
            float w = 0.f;
            if (gk < K) w = W[(size_t)(c0 + col) * K + gk];
            Ws[kk][col] = w;
        }
        __syncthreads();
        #pragma unroll
        for (int k4 = 0; k4 < BK / 4; ++k4) {
            float4 xr[8];
            #pragma unroll
            for (int i = 0; i < 8; ++i)
                xr[i] = *(const float4*)&Xs[tr * 8 + i][k4 * 4];
            #pragma unroll
            for (int u = 0; u < 4; ++u) {
                float4 wv = *(const float4*)&Ws[k4 * 4 + u][tc * 4];
                #pragma unroll
                for (int i = 0; i < 8; ++i) {
                    float xv = ((const float*)&xr[i])[u];
                    acc[i][0] += xv * wv.x;
                    acc[i][1] += xv * wv.y;
                    acc[i][2] += xv * wv.z;
                    acc[i][3] += xv * wv.w;
                }
            }
        }
        __syncthreads();
    }
    const int gc = c0 + tc * 4;
    float4 bv = *(const float4*)&bias[gc];
    #pragma unroll
    for (int i = 0; i < 8; ++i) {
        int gr = m0 + tr * 8 + i;
        float4 v;
        v.x = acc[i][0] + bv.x; v.y = acc[i][1] + bv.y;
        v.z = acc[i][2] + bv.z; v.w = acc[i][3] + bv.w;
        if (EPI == EPI_RELU) {
            v.x = fmaxf(v.x, 0.f); v.y = fmaxf(v.y, 0.f);
            v.z = fmaxf(v.z, 0.f); v.w = fmaxf(v.w, 0.f);
        }
        if (EPI == EPI_RESID) {
            float4 rr = *(const float4*)&resid[(size_t)gr * ldo + gc];
            v.x += rr.x; v.y += rr.y; v.z += rr.z; v.w += rr.w;
        }
        *(float4*)&out[(size_t)gr * ldo + gc] = v;
    }
}

// ---------------------------------------------------------------------------
// Ce GEMM + e_ij = Dx[dst]+Ex[src]+Ce  (NO atomics — aggregation moved to agg_k)
// ---------------------------------------------------------------------------
__launch_bounds__(256, 2)
__global__ void ce_eij_k(const float* __restrict__ he,
                         const float* __restrict__ W,
                         const float* __restrict__ bias,
                         const float* __restrict__ Dx,
                         const float* __restrict__ Exm,
                         const int* __restrict__ esrc,
                         const int* __restrict__ edst,
                         float* __restrict__ e_ij)
{
    __shared__ float Xs[BM][36];
    __shared__ float Ws[BK][132];
    const int tid = threadIdx.x;
    const int m0  = blockIdx.x * BM;
    const int tr  = tid >> 5;
    const int tc  = tid & 31;
    float acc[8][4] = {};
    for (int kt = 0; kt < 4; ++kt) {
        const int k0 = kt * BK;
        #pragma unroll
        for (int i = 0; i < 8; ++i) {
            int idx = tid + i * 256;
            int r = idx >> 5, kk = idx & 31;
            Xs[r][kk] = he[(size_t)(m0 + r) * 128 + k0 + kk];
        }
        #pragma unroll
        for (int i = 0; i < 16; ++i) {
            int idx = tid + i * 256;
            int col = idx >> 5, kk = idx & 31;
            Ws[kk][col] = W[(size_t)col * 128 + k0 + kk];
        }
        __syncthreads();
        #pragma unroll
        for (int k4 = 0; k4 < BK / 4; ++k4) {
            float4 xr[8];
            #pragma unroll
            for (int i = 0; i < 8; ++i)
                xr[i] = *(const float4*)&Xs[tr * 8 + i][k4 * 4];
            #pragma unroll
            for (int u = 0; u < 4; ++u) {
                float4 wv = *(const float4*)&Ws[k4 * 4 + u][tc * 4];
                #pragma unroll
                for (int i = 0; i < 8; ++i) {
                    float xv = ((const float*)&xr[i])[u];
                    acc[i][0] += xv * wv.x;
                    acc[i][1] += xv * wv.y;
                    acc[i][2] += xv * wv.z;
                    acc[i][3] += xv * wv.w;
                }
            }
        }
        __syncthreads();
    }
    const int gc = tc * 4;
    float4 bv = *(const float4*)&bias[gc];
    #pragma unroll
    for (int i = 0; i < 8; ++i) {
        int gr = m0 + tr * 8 + i;
        int s = esrc[gr], d = edst[gr];
        float4 dv = *(const float4*)&Dx [(size_t)d * 128 + gc];
        float4 ev = *(const float4*)&Exm[(size_t)s * 128 + gc];
        float4 e4;
        e4.x = acc[i][0] + bv.x + dv.x + ev.x;
        e4.y = acc[i][1] + bv.y + dv.y + ev.y;
        e4.z = acc[i][2] + bv.z + dv.z + ev.z;
        e4.w = acc[i][3] + bv.w + dv.w + ev.w;
        *(float4*)&e_ij[(size_t)gr * 128 + gc] = e4;
    }
}

// ---------------------------------------------------------------------------
// CSR build: deg histogram -> exclusive scan -> scatter permutation
// ---------------------------------------------------------------------------
__global__ void hist_k(const int* __restrict__ edst, int* __restrict__ deg)
{
    for (int e = blockIdx.x * 256 + threadIdx.x; e < EE; e += gridDim.x * 256)
        atomicAdd(&deg[edst[e]], 1);
}

__global__ void scan_k(const int* __restrict__ deg,
                       int* __restrict__ offs, int* __restrict__ cursor)
{
    __shared__ int tsum[256];
    const int t = threadIdx.x;
    int s = 0;
    #pragma unroll
    for (int j = 0; j < 32; ++j) s += deg[t * 32 + j];
    tsum[t] = s;
    __syncthreads();
    if (t == 0) {
        int run = 0;
        for (int i = 0; i < 256; ++i) { int v = tsum[i]; tsum[i] = run; run += v; }
        offs[8192] = run;
    }
    __syncthreads();
    int run = tsum[t];
    #pragma unroll
    for (int j = 0; j < 32; ++j) {
        int b = t * 32 + j;
        offs[b] = run; cursor[b] = run;
        run += deg[b];
    }
}

__global__ void scatter_k(const int* __restrict__ edst,
                          int* __restrict__ cursor, int* __restrict__ eperm)
{
    for (int e = blockIdx.x * 256 + threadIdx.x; e < EE; e += gridDim.x * 256) {
        int pos = atomicAdd(&cursor[edst[e]], 1);
        eperm[pos] = e;
    }
}

// ---------------------------------------------------------------------------
// Gather aggregation: one wave per node. lane l owns channels {2l, 2l+1}.
// xpre[n] = Ax[n] + sum(sigma*Bx[src]) / (sum(sigma)+1e-6)
// ---------------------------------------------------------------------------
__launch_bounds__(256, 4)
__global__ void agg_k(const float* __restrict__ e_ij,
                      const float* __restrict__ Bx,
                      const float* __restrict__ Ax,
                      const int* __restrict__ esrc,
                      const int* __restrict__ offs,
                      const int* __restrict__ eperm,
                      float* __restrict__ xpre)
{
    const int n    = blockIdx.x * 4 + (threadIdx.x >> 6);
    const int lane = threadIdx.x & 63;
    const int beg = offs[n], end = offs[n + 1];
    float nx = 0.f, ny = 0.f, dx = 0.f, dy = 0.f;
    const float2* eij2 = (const float2*)e_ij;
    const float2* bx2  = (const float2*)Bx;
    int idx = beg;
    for (; idx + 1 < end; idx += 2) {
        int e0 = eperm[idx], e1 = eperm[idx + 1];
        int s0 = esrc[e0],   s1 = esrc[e1];
        float2 ev0 = eij2[(size_t)e0 * 64 + lane];
        float2 ev1 = eij2[(size_t)e1 * 64 + lane];
        float2 b0  = bx2[(size_t)s0 * 64 + lane];
        float2 b1  = bx2[(size_t)s1 * 64 + lane];
        float g0x = 1.f / (1.f + __expf(-ev0.x));
        float g0y = 1.f / (1.f + __expf(-ev0.y));
        float g1x = 1.f / (1.f + __expf(-ev1.x));
        float g1y = 1.f / (1.f + __expf(-ev1.y));
        nx += g0x * b0.x + g1x * b1.x;
        ny += g0y * b0.y + g1y * b1.y;
        dx += g0x + g1x;
        dy += g0y + g1y;
    }
    if (idx < end) {
        int e0 = eperm[idx];
        int s0 = esrc[e0];
        float2 ev0 = eij2[(size_t)e0 * 64 + lane];
        float2 b0  = bx2[(size_t)s0 * 64 + lane];
        float g0x = 1.f / (1.f + __expf(-ev0.x));
        float g0y = 1.f / (1.f + __expf(-ev0.y));
        nx += g0x * b0.x; ny += g0y * b0.y;
        dx += g0x;        dy += g0y;
    }
    float2 a = ((const float2*)Ax)[(size_t)n * 64 + lane];
    float2 o;
    o.x = a.x + nx / (dx + 1e-6f);
    o.y = a.y + ny / (dy + 1e-6f);
    ((float2*)xpre)[(size_t)n * 64 + lane] = o;
}

// ---------------------------------------------------------------------------
// Per-channel sum/sumsq over rows (for batchnorm stats)
// ---------------------------------------------------------------------------
__global__ void bnstats_k(const float* __restrict__ x, int M,
                          float* __restrict__ sum, float* __restrict__ sumsq)
{
    const int col  = threadIdx.x & 127;
    const int half = threadIdx.x >> 7;
    const int stride = 2 * gridDim.x;
    float s = 0.f, ss = 0.f;
    for (int r = blockIdx.x * 2 + half; r < M; r += stride) {
        float v = x[(size_t)r * 128 + col];
        s += v; ss += v * v;
    }
    __shared__ float Ss[2][128], SSs[2][128];
    Ss[half][col] = s; SSs[half][col] = ss;
    __syncthreads();
    if (half == 0) {
        atomicAdd(&sum[col],   Ss[0][col] + Ss[1][col]);
        atomicAdd(&sumsq[col], SSs[0][col] + SSs[1][col]);
    }
}

__global__ void bnfinal_k(const float* esum, const float* esumsq,
                          const float* xsum, const float* xsumsq,
                          const float* eg, const float* eb,
                          const float* xg, const float* xb,
                          float* esc, float* esh, float* xsc, float* xsh)
{
    int c = threadIdx.x;
    float me = esum[c] * (1.f / EE);
    float ve = esumsq[c] * (1.f / EE) - me * me;
    float se = eg[c] * rsqrtf(ve + 1e-5f);
    esc[c] = se; esh[c] = eb[c] - me * se;
    float mx = xsum[c] * (1.f / NN);
    float vx = xsumsq[c] * (1.f / NN) - mx * mx;
    float sx = xg[c] * rsqrtf(vx + 1e-5f);
    xsc[c] = sx; xsh[c] = xb[c] - mx * sx;
}

__global__ void xpost_k(const float* __restrict__ xpre,
                        const float* __restrict__ hv,
                        const float* __restrict__ xsc,
                        const float* __restrict__ xsh,
                        float* __restrict__ xfin)
{
    int i = blockIdx.x * 1024 + threadIdx.x * 4;
    int c = i & 127;
    float4 v  = *(const float4*)&xpre[i];
    float4 s4 = *(const float4*)&xsc[c];
    float4 h4 = *(const float4*)&xsh[c];
    float4 r4 = *(const float4*)&hv[i];
    float4 o;
    o.x = fmaxf(v.x * s4.x + h4.x, 0.f) + r4.x;
    o.y = fmaxf(v.y * s4.y + h4.y, 0.f) + r4.y;
    o.z = fmaxf(v.z * s4.z + h4.z, 0.f) + r4.z;
    o.w = fmaxf(v.w * s4.w + h4.w, 0.f) + r4.w;
    *(float4*)&xfin[i] = o;
}

// ---------------------------------------------------------------------------
// e = relu(bn(e_ij)) + he (he pre-stored in e_out) ; delta readout fused
// ---------------------------------------------------------------------------
__launch_bounds__(256, 2)
__global__ void epost_delta_k(const float* __restrict__ e_ij,
                              float* __restrict__ e_out,
                              const float* __restrict__ esc,
                              const float* __restrict__ esh,
                              const float* __restrict__ w1,
                              const float* __restrict__ b1,
                              const float* __restrict__ w2,
                              const float* __restrict__ b2,
                              float* __restrict__ delta)
{
    __shared__ float Es[BM][132];
    __shared__ float Ws[BK][132];
    __shared__ float red[BM][33];
    __shared__ float w2s[128], b1s[128];
    const int tid = threadIdx.x;
    const int m0  = blockIdx.x * BM;
    const int tr  = tid >> 5;
    const int tc  = tid & 31;
    const int gc  = tc * 4;
    if (tid < 128) { w2s[tid] = w2[tid]; b1s[tid] = b1[tid]; }
    float4 sc4 = *(const float4*)&esc[gc];
    float4 sh4 = *(const float4*)&esh[gc];
    #pragma unroll
    for (int i = 0; i < 8; ++i) {
        int gr = m0 + tr * 8 + i;
        float4 ij  = *(const float4*)&e_ij [(size_t)gr * 128 + gc];
        float4 hev = *(const float4*)&e_out[(size_t)gr * 128 + gc];
        float4 ev;
        ev.x = fmaxf(ij.x * sc4.x + sh4.x, 0.f) + hev.x;
        ev.y = fmaxf(ij.y * sc4.y + sh4.y, 0.f) + hev.y;
        ev.z = fmaxf(ij.z * sc4.z + sh4.z, 0.f) + hev.z;
        ev.w = fmaxf(ij.w * sc4.w + sh4.w, 0.f) + hev.w;
        *(float4*)&e_out[(size_t)gr * 128 + gc] = ev;
        *(float4*)&Es[tr * 8 + i][gc] = ev;
    }
    __syncthreads();
    float acc[8][4] = {};
    for (int kt = 0; kt < 4; ++kt) {
        const int k0 = kt * 32;
        if (kt > 0) __syncthreads();
        #pragma unroll
        for (int i = 0; i < 16; ++i) {
            int idx = tid + i * 256;
            int col = idx >> 5, kk = idx & 31;
            Ws[kk][col] = w1[(size_t)col * 128 + k0 + kk];
        }
        __syncthreads();
        #pragma unroll
        for (int k4 = 0; k4 < 8; ++k4) {
            float4 xr[8];
            #pragma unroll
            for (int i = 0; i < 8; ++i)
                xr[i] = *(const float4*)&Es[tr * 8 + i][k0 + k4 * 4];
            #pragma unroll
            for (int u = 0; u < 4; ++u) {
                float4 wv = *(const float4*)&Ws[k4 * 4 + u][tc * 4];
                #pragma unroll
                for (int i = 0; i < 8; ++i) {
                    float xv = ((const float*)&xr[i])[u];
                    acc[i][0] += xv * wv.x;
                    acc[i][1] += xv * wv.y;
                    acc[i][2] += xv * wv.z;
                    acc[i][3] += xv * wv.w;
                }
            }
        }
    }
    __syncthreads();
    #pragma unroll
    for (int i = 0; i < 8; ++i) {
        float p = 0.f;
        #pragma unroll
        for (int j = 0; j < 4; ++j) {
            float t = fmaxf(acc[i][j] + b1s[gc + j], 0.f);
            p += t * w2s[gc + j];
        }
        red[tr * 8 + i][tc] = p;
    }
    __syncthreads();
    if (tid < 64) {
        float s = 0.f;
        #pragma unroll
        for (int c = 0; c < 32; ++c) s += red[tid][c];
        delta[m0 + tid] = s + b2[0];
    }
}

// ---------------------------------------------------------------------------
// batch_vec -> starts/counts (batch_vec sorted)
// ---------------------------------------------------------------------------
__global__ void meta_k(const int* __restrict__ bvec, int* starts, int* counts)
{
    __shared__ int cnt[BB];
    if (threadIdx.x < BB) cnt[threadIdx.x] = 0;
    __syncthreads();
    for (int i = threadIdx.x; i < NN; i += 256) atomicAdd(&cnt[bvec[i]], 1);
    __syncthreads();
    if (threadIdx.x == 0) {
        int s = 0;
        for (int b = 0; b < BB; ++b) { starts[b] = s; counts[b] = cnt[b]; s += cnt[b]; }
    }
}

// ---------------------------------------------------------------------------
// Flash attention, per (graph, head, 32-query tile). hd=32, keys tiled by 64.
// ---------------------------------------------------------------------------
__launch_bounds__(256, 2)
__global__ void attn_k(const float* __restrict__ qkv,
                       const int* __restrict__ starts,
                       const int* __restrict__ counts,
                       float* __restrict__ ctx)
{
    const int b  = blockIdx.x;
    const int h  = blockIdx.y;
    const int qt = blockIdx.z;
    const int cnt = counts[b];
    const int st  = starts[b];
    const int q0  = qt * 32;
    if (q0 >= cnt) return;
    __shared__ float Ks[64][36];
    __shared__ float Vs[64][36];
    __shared__ float Ps[32][68];
    const int tid = threadIdx.x;
    const int qi  = tid >> 3;
    const int sub = tid & 7;
    const int qrow = q0 + qi;
    float4 qv[8];
    if (qrow < cnt) {
        const float* qp = &qkv[(size_t)(st + qrow) * 384 + h * 32];
        #pragma unroll
        for (int c4 = 0; c4 < 8; ++c4) qv[c4] = *(const float4*)&qp[c4 * 4];
    } else {
        #pragma unroll
        for (int c4 = 0; c4 < 8; ++c4) qv[c4] = make_float4(0.f, 0.f, 0.f, 0.f);
    }
    float m = -1e30f, l = 0.f;
    float a0 = 0.f, a1 = 0.f, a2 = 0.f, a3 = 0.f;
    const int nkt = (cnt + 63) >> 6;
    for (int kt = 0; kt < nkt; ++kt) {
        const int kk0 = kt * 64;
        __syncthreads();
        #pragma unroll
        for (int i = 0; i < 8; ++i) {
            int idx = tid + i * 256;
            int r = idx >> 5, c = idx & 31;
            int kg = kk0 + r;
            float kvv = 0.f, vvv = 0.f;
            if (kg < cnt) {
                size_t base = (size_t)(st + kg) * 384 + h * 32;
                kvv = qkv[base + 128 + c];
                vvv = qkv[base + 256 + c];
            }
            Ks[r][c] = kvv;
            Vs[r][c] = vvv;
        }
        __syncthreads();
        float p[8];
        float tmax = -1e30f;
        #pragma unroll
        for (int j2 = 0; j2 < 8; ++j2) {
            int j = sub * 8 + j2;
            float s = 0.f;
            #pragma unroll
            for (int c4 = 0; c4 < 8; ++c4) {
                float4 kv4 = *(const float4*)&Ks[j][c4 * 4];
                s += qv[c4].x * kv4.x + qv[c4].y * kv4.y
                   + qv[c4].z * kv4.z + qv[c4].w * kv4.w;
            }
            s *= 0.17677669529663687f;
            if (kk0 + j >= cnt) s = -1e30f;
            p[j2] = s;
            tmax = fmaxf(tmax, s);
        }
        #pragma unroll
        for (int d = 1; d < 8; d <<= 1) tmax = fmaxf(tmax, __shfl_xor(tmax, d));
        const float mnew = fmaxf(m, tmax);
        const float corr = __expf(m - mnew);
        float tsum = 0.f;
        #pragma unroll
        for (int j2 = 0; j2 < 8; ++j2) {
            float pe = __expf(p[j2] - mnew);
            p[j2] = pe;
            tsum += pe;
        }
        #pragma unroll
        for (int d = 1; d < 8; d <<= 1) tsum += __shfl_xor(tsum, d);
        l = l * corr + tsum;
        m = mnew;
        a0 *= corr; a1 *= corr; a2 *= corr; a3 *= corr;
        #pragma unroll
        for (int j2 = 0; j2 < 8; ++j2) Ps[qi][sub * 8 + j2] = p[j2];
        __syncthreads();
        for (int j = 0; j < 64; ++j) {
            float pj = Ps[qi][j];
            float4 vv = *(const float4*)&Vs[j][sub * 4];
            a0 += pj * vv.x; a1 += pj * vv.y; a2 += pj * vv.z; a3 += pj * vv.w;
        }
    }
    if (qrow < cnt) {
        float inv = 1.f / l;
        float4 o = make_float4(a0 * inv, a1 * inv, a2 * inv, a3 * inv);
        *(float4*)&ctx[(size_t)(st + qrow) * 128 + h * 32 + sub * 4] = o;
    }
}

// ---------------------------------------------------------------------------
// LayerNorm over rows of 128 (eps 1e-5), one wave per row
// ---------------------------------------------------------------------------
__global__ void ln_k(const float* __restrict__ x,
                     const float* __restrict__ g,
                     const float* __restrict__ b,
                     float* __restrict__ out, int M)
{
    int row  = blockIdx.x * 4 + (threadIdx.x >> 6);
    int lane = threadIdx.x & 63;
    if (row >= M) return;
    float2 v = *(const float2*)&x[(size_t)row * 128 + lane * 2];
    float s  = v.x + v.y;
    float ss = v.x * v.x + v.y * v.y;
    #pragma unroll
    for (int d = 1; d < 64; d <<= 1) {
        s  += __shfl_xor(s, d);
        ss += __shfl_xor(ss, d);
    }
    float mean = s * (1.f / 128.f);
    float var  = ss * (1.f / 128.f) - mean * mean;
    float inv  = rsqrtf(var + 1e-5f);
    float2 o;
    o.x = (v.x - mean) * inv * g[lane * 2 + 0] + b[lane * 2 + 0];
    o.y = (v.y - mean) * inv * g[lane * 2 + 1] + b[lane * 2 + 1];
    *(float2*)&out[(size_t)row * 128 + lane * 2] = o;
}

extern "C" void kernel_launch(void* const* d_in, const int* in_sizes, int n_in,
                              void* d_out, int out_size, void* d_ws, size_t ws_size,
                              hipStream_t stream) {
    (void)in_sizes; (void)n_in; (void)out_size; (void)ws_size;
    const float* h_v   = (const float*)d_in[0];
    const float* h_e   = (const float*)d_in[1];
    const float* rho_v = (const float*)d_in[2];
    const float* f_k   = (const float*)d_in[3];
    const float* ei_w  = (const float*)d_in[4];
    const float* ei_b  = (const float*)d_in[5];
    const float* ni_w  = (const float*)d_in[6];
    const float* ni_b  = (const float*)d_in[7];
    const float* Aw = (const float*)d_in[8],  *Ab = (const float*)d_in[9];
    const float* Bw = (const float*)d_in[10], *Bb = (const float*)d_in[11];
    const float* Cw = (const float*)d_in[12], *Cb = (const float*)d_in[13];
    const float* Dw = (const float*)d_in[14], *Db = (const float*)d_in[15];
    const float* Ew = (const float*)d_in[16], *Eb = (const float*)d_in[17];
    const float* bnxg = (const float*)d_in[18], *bnxb = (const float*)d_in[19];
    const float* bneg = (const float*)d_in[20], *bneb = (const float*)d_in[21];
    const float* aiw = (const float*)d_in[22], *aib = (const float*)d_in[23];
    const float* aow = (const float*)d_in[24], *aob = (const float*)d_in[25];
    const float* ln1g = (const float*)d_in[26], *ln1b = (const float*)d_in[27];
    const float* ln2g = (const float*)d_in[28], *ln2b = (const float*)d_in[29];
    const float* f1w = (const float*)d_in[30], *f1b = (const float*)d_in[31];
    const float* f2w = (const float*)d_in[32], *f2b = (const float*)d_in[33];
    const float* row1 = (const float*)d_in[34], *rob1 = (const float*)d_in[35];
    const float* row2 = (const float*)d_in[36], *rob2 = (const float*)d_in[37];
    const int* eidx = (const int*)d_in[38];
    const int* bvec = (const int*)d_in[39];
    const int* esrc = eidx;
    const int* edst = eidx + EE;

    float* ws = (float*)d_ws;
    size_t o = 0;
    float* e_ij   = ws + o; o += (size_t)EE * HH;
    float* hv     = ws + o; o += (size_t)NN * HH;
    float* Ax     = ws + o; o += (size_t)NN * HH;
    float* Bx     = ws + o; o += (size_t)NN * HH;
    float* Dx     = ws + o; o += (size_t)NN * HH;
    float* Exm    = ws + o; o += (size_t)NN * HH;
    float* csrf   = ws + o; o += (size_t)NN * HH;   // CSR space (ints), 4MB
    float* spare  = ws + o; o += (size_t)NN * HH;   // unused (keeps f1 span)
    float* x_fin  = ws + o; o += (size_t)NN * HH;
    float* qkvb   = ws + o; o += (size_t)3 * NN * HH;
    float* ctx    = ws + o; o += (size_t)NN * HH;
    float* xd1    = ws + o; o += (size_t)NN * HH;
    float* esum   = ws + o; o += 128;
    float* esumsq = ws + o; o += 128;
    float* xsum   = ws + o; o += 128;
    float* xsumsq = ws + o; o += 128;
    float* esc    = ws + o; o += 128;
    float* esh    = ws + o; o += 128;
    float* xsc    = ws + o; o += 128;
    float* xsh    = ws + o; o += 128;
    int*   meta   = (int*)(ws + o); o += 32;
    (void)spare;
    // CSR arrays inside csrf (lifetime: before FFN's f1 use of this span)
    int* eperm  = (int*)csrf;            // EE ints
    int* deg    = eperm + EE;            // 8192
    int* offs   = deg + 8192;            // 8193
    int* cursor = offs + 8193;           // 8192
    // aliases (lifetimes verified disjoint):
    float* xpre = Ax;          // agg_k writes Ax in place (read+write same elem)
    float* f1   = Bx;          // spans Bx,Dx,Exm,csrf (N*512 floats) — used after agg
    float* tmp1 = qkvb;        // post-attention residual buffer
    float* tmp2 = ctx;         // post-ffn residual buffer

    float* out_x     = (float*)d_out;
    float* he        = out_x + (size_t)NN * HH;
    float* out_delta = he + (size_t)EE * HH;

    hipMemsetAsync(deg, 0, 8192 * sizeof(int), stream);
    hipMemsetAsync(esum, 0, 4 * 128 * sizeof(float), stream);

    dim3 blk(256);
    meta_k<<<1, blk, 0, stream>>>(bvec, meta, meta + BB);
    // CSR build (independent of GEMMs)
    hist_k<<<256, blk, 0, stream>>>(edst, deg);
    scan_k<<<1, blk, 0, stream>>>(deg, offs, cursor);
    scatter_k<<<512, blk, 0, stream>>>(edst, cursor, eperm);

    // hv = [h_v, rho_v] @ ni_w^T + ni_b
    gemm_k<X_NODE, EPI_NONE><<<dim3(NN / BM, 1), blk, 0, stream>>>(
        h_v, ni_w, ni_b, hv, NN, 129, 128, nullptr, rho_v, nullptr, nullptr, nullptr);
    // he = [h_e, rho[src], rho[dst], f_k] @ ei_w^T + ei_b
    gemm_k<X_EDGE, EPI_NONE><<<dim3(EE / BM, 1), blk, 0, stream>>>(
        h_e, ei_w, ei_b, he, EE, 131, 128, nullptr, rho_v, f_k, esrc, edst);
    // A/B/D/E projections of hv
    gemm_k<X_PLAIN, EPI_NONE><<<dim3(NN / BM, 1), blk, 0, stream>>>(
        hv, Aw, Ab, Ax, NN, 128, 128, nullptr, nullptr, nullptr, nullptr, nullptr);
    gemm_k<X_PLAIN, EPI_NONE><<<dim3(NN / BM, 1), blk, 0, stream>>>(
        hv, Bw, Bb, Bx, NN, 128, 128, nullptr, nullptr, nullptr, nullptr, nullptr);
    gemm_k<X_PLAIN, EPI_NONE><<<dim3(NN / BM, 1), blk, 0, stream>>>(
        hv, Dw, Db, Dx, NN, 128, 128, nullptr, nullptr, nullptr, nullptr, nullptr);
    gemm_k<X_PLAIN, EPI_NONE><<<dim3(NN / BM, 1), blk, 0, stream>>>(
        hv, Ew, Eb, Exm, NN, 128, 128, nullptr, nullptr, nullptr, nullptr, nullptr);
    // Ce GEMM + e_ij (no atomics)
    ce_eij_k<<<dim3(EE / BM), blk, 0, stream>>>(
        he, Cw, Cb, Dx, Exm, esrc, edst, e_ij);
    // gather aggregation -> xpre (folds old xcombine)
    agg_k<<<NN / 4, blk, 0, stream>>>(e_ij, Bx, Ax, esrc, offs, eperm, xpre);
    // batchnorm stats
    bnstats_k<<<1024, blk, 0, stream>>>(e_ij, EE, esum, esumsq);
    bnstats_k<<<64, blk, 0, stream>>>(xpre, NN, xsum, xsumsq);
    bnfinal_k<<<1, 128, 0, stream>>>(esum, esumsq, xsum, xsumsq,
                                     bneg, bneb, bnxg, bnxb, esc, esh, xsc, xsh);
    xpost_k<<<(NN * HH) / 1024, blk, 0, stream>>>(xpre, hv, xsc, xsh, x_fin);
    // e (+residual he) + fused delta readout
    epost_delta_k<<<dim3(EE / BM), blk, 0, stream>>>(
        e_ij, he, esc, esh, row1, rob1, row2, rob2, out_delta);
    // attention stream
    gemm_k<X_PLAIN, EPI_NONE><<<dim3(NN / BM, 3), blk, 0, stream>>>(
        x_fin, aiw, aib, qkvb, NN, 128, 384, nullptr, nullptr, nullptr, nullptr, nullptr);
    attn_k<<<dim3(BB, NHEADS, 32), blk, 0, stream>>>(qkvb, meta, meta + BB, ctx);
    gemm_k<X_PLAIN, EPI_RESID><<<dim3(NN / BM, 1), blk, 0, stream>>>(
        ctx, aow, aob, tmp1, NN, 128, 128, x_fin, nullptr, nullptr, nullptr, nullptr);
    ln_k<<<NN / 4, blk, 0, stream>>>(tmp1, ln1g, ln1b, xd1, NN);
    gemm_k<X_PLAIN, EPI_RELU><<<dim3(NN / BM, 4), blk, 0, stream>>>(
        xd1, f1w, f1b, f1, NN, 128, 512, nullptr, nullptr, nullptr, nullptr, nullptr);
    gemm_k<X_PLAIN, EPI_RESID><<<dim3(NN / BM, 1), blk, 0, stream>>>(
        f1, f2w, f2b, tmp2, NN, 512, 128, xd1, nullptr, nullptr, nullptr, nullptr);
    ln_k<<<NN / 4, blk, 0, stream>>>(tmp2, ln2g, ln2b, out_x, NN);
}

// Round 7
// 1482.585 us; speedup vs baseline: 2.6103x; 1.6371x over previous
//
#include <hip/hip_runtime.h>
#include <cstdint>
#include <cstddef>

#define NN 8192
#define EE 524288
#define HH 128
#define BB 16
#define NHEADS 4

enum { X_PLAIN = 0, X_NODE = 1, X_EDGE = 2 };
enum { EPI_NONE = 0, EPI_RELU = 1, EPI_RESID = 2 };

typedef short s16x8 __attribute__((ext_vector_type(8)));
typedef float f32x4 __attribute__((ext_vector_type(4)));

// fp32 -> bf16 RNE
__device__ __forceinline__ ushort f2bf(float x) {
    union { float f; uint u; } v; v.f = x;
    uint r = (v.u + 0x7FFFu + ((v.u >> 16) & 1u)) >> 16;
    return (ushort)r;
}
__device__ __forceinline__ uint pk2(float a, float b) {
    return (uint)f2bf(a) | ((uint)f2bf(b) << 16);
}
// swizzled LDS index (ushort units); rows stride 128 bf16. XOR bits 3-5 kill
// the 16-way bank conflict of stride-256B ds_read_b128 (guide §6 G4).
#define SWZ(r, k) ((((r) * 128) + (k)) ^ (((r) & 7) << 3))

// stage 64xK-chunk of X and 128xK-chunk of W (fp32 global -> bf16 swizzled LDS)
__device__ __forceinline__ void stage_tiles(const float* __restrict__ X,
                                            const float* __restrict__ W,
                                            int m0, int c0, int K, int Ksrc, int k0,
                                            ushort* Xs, ushort* Ws, int tid)
{
    for (int g = tid; g < 1024; g += 256) {
        int row = g >> 4, k8 = (g & 15) * 8;
        const float* s = X + (size_t)(m0 + row) * K + k0 + k8;
        float4 a = *(const float4*)s, b = *(const float4*)(s + 4);
        uint4 p;
        p.x = pk2(a.x, a.y); p.y = pk2(a.z, a.w);
        p.z = pk2(b.x, b.y); p.w = pk2(b.z, b.w);
        *(uint4*)&Xs[SWZ(row, k8)] = p;
    }
    if ((Ksrc & 3) == 0) {
        for (int g = tid; g < 2048; g += 256) {
            int col = g >> 4, k8 = (g & 15) * 8;
            const float* s = W + (size_t)(c0 + col) * Ksrc + k0 + k8;
            float4 a = *(const float4*)s, b = *(const float4*)(s + 4);
            uint4 p;
            p.x = pk2(a.x, a.y); p.y = pk2(a.z, a.w);
            p.z = pk2(b.x, b.y); p.w = pk2(b.z, b.w);
            *(uint4*)&Ws[SWZ(col, k8)] = p;
        }
    } else {  // odd source stride (K=129/131) -> scalar loads
        for (int g = tid; g < 2048; g += 256) {
            int col = g >> 4, k8 = (g & 15) * 8;
            const float* s = W + (size_t)(c0 + col) * Ksrc + k0 + k8;
            uint4 p;
            p.x = pk2(s[0], s[1]); p.y = pk2(s[2], s[3]);
            p.z = pk2(s[4], s[5]); p.w = pk2(s[6], s[7]);
            *(uint4*)&Ws[SWZ(col, k8)] = p;
        }
    }
}

// 128-K-chunk MFMA core: 4 waves (2x2), per wave 32x64 output, 2x4 fragments
__device__ __forceinline__ void mfma_core(const ushort* Xs, const ushort* Ws,
                                          int wr, int wc, int lr, int lg,
                                          f32x4 acc[2][4])
{
    #pragma unroll
    for (int ks = 0; ks < 4; ++ks) {
        int kb = ks * 32 + lg * 8;
        s16x8 af[2], bfr[4];
        #pragma unroll
        for (int mf = 0; mf < 2; ++mf)
            af[mf] = *(const s16x8*)&Xs[SWZ(wr * 32 + mf * 16 + lr, kb)];
        #pragma unroll
        for (int nf = 0; nf < 4; ++nf)
            bfr[nf] = *(const s16x8*)&Ws[SWZ(wc * 64 + nf * 16 + lr, kb)];
        #pragma unroll
        for (int mf = 0; mf < 2; ++mf)
            #pragma unroll
            for (int nf = 0; nf < 4; ++nf)
                acc[mf][nf] = __builtin_amdgcn_mfma_f32_16x16x32_bf16(
                    af[mf], bfr[nf], acc[mf][nf], 0, 0, 0);
    }
}

// ---------------------------------------------------------------------------
// MFMA GEMM: out[M][ldo slice] = bf16(X[M][K]) @ bf16(W[N][Ksrc])^T + bias
// K-tail (Ksrc>K) columns applied as exact fp32 rank-k epilogue correction.
// ---------------------------------------------------------------------------
template<int XMODE, int EPI>
__launch_bounds__(256, 2)
__global__ void mgemm_k(const float* __restrict__ X, const float* __restrict__ W,
                        const float* __restrict__ bias, float* __restrict__ out,
                        int K, int Ksrc, int ldo,
                        const float* __restrict__ resid,
                        const float* __restrict__ rho,
                        const float* __restrict__ fk,
                        const int* __restrict__ esrc,
                        const int* __restrict__ edst)
{
    __shared__ ushort Xs[64 * 128];
    __shared__ ushort Ws[128 * 128];
    const int tid = threadIdx.x;
    const int m0 = blockIdx.x * 64, c0 = blockIdx.y * 128;
    const int l = tid & 63, wid = tid >> 6;
    const int wr = wid >> 1, wc = wid & 1, lr = l & 15, lg = l >> 4;
    f32x4 acc[2][4] = {};
    for (int k0 = 0; k0 < K; k0 += 128) {
        if (k0) __syncthreads();
        stage_tiles(X, W, m0, c0, K, Ksrc, k0, Xs, Ws, tid);
        __syncthreads();
        mfma_core(Xs, Ws, wr, wc, lr, lg, acc);
    }
    float wt0[4], wt1[4], wt2[4];
    if (XMODE != X_PLAIN) {
        #pragma unroll
        for (int nf = 0; nf < 4; ++nf) {
            int gc = c0 + wc * 64 + nf * 16 + lr;
            wt0[nf] = W[(size_t)gc * Ksrc + 128];
            if (XMODE == X_EDGE) {
                wt1[nf] = W[(size_t)gc * Ksrc + 129];
                wt2[nf] = W[(size_t)gc * Ksrc + 130];
            }
        }
    }
    #pragma unroll
    for (int mf = 0; mf < 2; ++mf)
    #pragma unroll
    for (int i = 0; i < 4; ++i) {
        int gr = m0 + wr * 32 + mf * 16 + lg * 4 + i;
        float ra0 = 0.f, ra1 = 0.f, ra2 = 0.f;
        if (XMODE == X_NODE) ra0 = rho[gr];
        if (XMODE == X_EDGE) { ra0 = rho[esrc[gr]]; ra1 = rho[edst[gr]]; ra2 = fk[gr]; }
        #pragma unroll
        for (int nf = 0; nf < 4; ++nf) {
            int gc = c0 + wc * 64 + nf * 16 + lr;
            float v = acc[mf][nf][i] + bias[gc];
            if (XMODE == X_NODE) v += ra0 * wt0[nf];
            if (XMODE == X_EDGE) v += ra0 * wt0[nf] + ra1 * wt1[nf] + ra2 * wt2[nf];
            if (EPI == EPI_RELU) v = fmaxf(v, 0.f);
            if (EPI == EPI_RESID) v += resid[(size_t)gr * ldo + gc];
            out[(size_t)gr * ldo + gc] = v;
        }
    }
}

// ---------------------------------------------------------------------------
// Ce MFMA GEMM + e_ij = Ce + Dx[dst] + Ex[src]   (K = 128, N = 128)
// ---------------------------------------------------------------------------
__launch_bounds__(256, 2)
__global__ void ce_mk(const float* __restrict__ he, const float* __restrict__ W,
                      const float* __restrict__ bias,
                      const float* __restrict__ Dx, const float* __restrict__ Exm,
                      const int* __restrict__ esrc, const int* __restrict__ edst,
                      float* __restrict__ e_ij)
{
    __shared__ ushort Xs[64 * 128];
    __shared__ ushort Ws[128 * 128];
    const int tid = threadIdx.x;
    const int m0 = blockIdx.x * 64;
    const int l = tid & 63, wid = tid >> 6;
    const int wr = wid >> 1, wc = wid & 1, lr = l & 15, lg = l >> 4;
    f32x4 acc[2][4] = {};
    stage_tiles(he, W, m0, 0, 128, 128, 0, Xs, Ws, tid);
    __syncthreads();
    mfma_core(Xs, Ws, wr, wc, lr, lg, acc);
    #pragma unroll
    for (int mf = 0; mf < 2; ++mf)
    #pragma unroll
    for (int i = 0; i < 4; ++i) {
        int gr = m0 + wr * 32 + mf * 16 + lg * 4 + i;
        int d = edst[gr], s = esrc[gr];
        #pragma unroll
        for (int nf = 0; nf < 4; ++nf) {
            int gc = wc * 64 + nf * 16 + lr;
            float v = acc[mf][nf][i] + bias[gc]
                    + Dx[(size_t)d * 128 + gc] + Exm[(size_t)s * 128 + gc];
            e_ij[(size_t)gr * 128 + gc] = v;
        }
    }
}

// ---------------------------------------------------------------------------
// delta = w2 . relu(e @ W1^T + b1) + b2   (MFMA + row reduction)
// ---------------------------------------------------------------------------
__launch_bounds__(256, 2)
__global__ void delta_mk(const float* __restrict__ e, const float* __restrict__ w1,
                         const float* __restrict__ b1, const float* __restrict__ w2,
                         const float* __restrict__ b2, float* __restrict__ delta)
{
    __shared__ ushort Xs[64 * 128];
    __shared__ ushort Ws[128 * 128];
    __shared__ float redS[64];
    const int tid = threadIdx.x;
    const int m0 = blockIdx.x * 64;
    const int l = tid & 63, wid = tid >> 6;
    const int wr = wid >> 1, wc = wid & 1, lr = l & 15, lg = l >> 4;
    if (tid < 64) redS[tid] = 0.f;
    f32x4 acc[2][4] = {};
    stage_tiles(e, w1, m0, 0, 128, 128, 0, Xs, Ws, tid);
    __syncthreads();
    mfma_core(Xs, Ws, wr, wc, lr, lg, acc);
    float b1v[4], w2v[4];
    #pragma unroll
    for (int nf = 0; nf < 4; ++nf) {
        int gc = wc * 64 + nf * 16 + lr;
        b1v[nf] = b1[gc]; w2v[nf] = w2[gc];
    }
    float pp[2][4];
    #pragma unroll
    for (int mf = 0; mf < 2; ++mf)
    #pragma unroll
    for (int i = 0; i < 4; ++i) {
        float p = 0.f;
        #pragma unroll
        for (int nf = 0; nf < 4; ++nf)
            p += fmaxf(acc[mf][nf][i] + b1v[nf], 0.f) * w2v[nf];
        pp[mf][i] = p;
    }
    #pragma unroll
    for (int d = 1; d < 16; d <<= 1)
        #pragma unroll
        for (int mf = 0; mf < 2; ++mf)
            #pragma unroll
            for (int i = 0; i < 4; ++i)
                pp[mf][i] += __shfl_xor(pp[mf][i], d);
    if (lr == 0) {
        #pragma unroll
        for (int mf = 0; mf < 2; ++mf)
            #pragma unroll
            for (int i = 0; i < 4; ++i)
                atomicAdd(&redS[wr * 32 + mf * 16 + lg * 4 + i], pp[mf][i]);
    }
    __syncthreads();
    if (tid < 64) delta[m0 + tid] = redS[tid] + b2[0];
}

// ---------------------------------------------------------------------------
// CSR build
// ---------------------------------------------------------------------------
__global__ void hist_k(const int* __restrict__ edst, int* __restrict__ deg)
{
    for (int e = blockIdx.x * 256 + threadIdx.x; e < EE; e += gridDim.x * 256)
        atomicAdd(&deg[edst[e]], 1);
}

__global__ void scan_k(const int* __restrict__ deg,
                       int* __restrict__ offs, int* __restrict__ cursor)
{
    __shared__ int tsum[256];
    const int t = threadIdx.x;
    int s = 0;
    #pragma unroll
    for (int j = 0; j < 32; ++j) s += deg[t * 32 + j];
    tsum[t] = s;
    __syncthreads();
    if (t == 0) {
        int run = 0;
        for (int i = 0; i < 256; ++i) { int v = tsum[i]; tsum[i] = run; run += v; }
        offs[8192] = run;
    }
    __syncthreads();
    int run = tsum[t];
    #pragma unroll
    for (int j = 0; j < 32; ++j) {
        int b = t * 32 + j;
        offs[b] = run; cursor[b] = run;
        run += deg[b];
    }
}

__global__ void scatter_k(const int* __restrict__ edst,
                          int* __restrict__ cursor, int* __restrict__ eperm)
{
    for (int e = blockIdx.x * 256 + threadIdx.x; e < EE; e += gridDim.x * 256) {
        int pos = atomicAdd(&cursor[edst[e]], 1);
        eperm[pos] = e;
    }
}

// ---------------------------------------------------------------------------
// Gather aggregation (one wave per node)
// ---------------------------------------------------------------------------
__launch_bounds__(256, 4)
__global__ void agg_k(const float* __restrict__ e_ij,
                      const float* __restrict__ Bx,
                      const float* __restrict__ Ax,
                      const int* __restrict__ esrc,
                      const int* __restrict__ offs,
                      const int* __restrict__ eperm,
                      float* __restrict__ xpre)
{
    const int n    = blockIdx.x * 4 + (threadIdx.x >> 6);
    const int lane = threadIdx.x & 63;
    const int beg = offs[n], end = offs[n + 1];
    float nx = 0.f, ny = 0.f, dx = 0.f, dy = 0.f;
    const float2* eij2 = (const float2*)e_ij;
    const float2* bx2  = (const float2*)Bx;
    int idx = beg;
    for (; idx + 1 < end; idx += 2) {
        int e0 = eperm[idx], e1 = eperm[idx + 1];
        int s0 = esrc[e0],   s1 = esrc[e1];
        float2 ev0 = eij2[(size_t)e0 * 64 + lane];
        float2 ev1 = eij2[(size_t)e1 * 64 + lane];
        float2 b0  = bx2[(size_t)s0 * 64 + lane];
        float2 b1  = bx2[(size_t)s1 * 64 + lane];
        float g0x = 1.f / (1.f + __expf(-ev0.x));
        float g0y = 1.f / (1.f + __expf(-ev0.y));
        float g1x = 1.f / (1.f + __expf(-ev1.x));
        float g1y = 1.f / (1.f + __expf(-ev1.y));
        nx += g0x * b0.x + g1x * b1.x;
        ny += g0y * b0.y + g1y * b1.y;
        dx += g0x + g1x;
        dy += g0y + g1y;
    }
    if (idx < end) {
        int e0 = eperm[idx];
        int s0 = esrc[e0];
        float2 ev0 = eij2[(size_t)e0 * 64 + lane];
        float2 b0  = bx2[(size_t)s0 * 64 + lane];
        float g0x = 1.f / (1.f + __expf(-ev0.x));
        float g0y = 1.f / (1.f + __expf(-ev0.y));
        nx += g0x * b0.x; ny += g0y * b0.y;
        dx += g0x;        dy += g0y;
    }
    float2 a = ((const float2*)Ax)[(size_t)n * 64 + lane];
    float2 o;
    o.x = a.x + nx / (dx + 1e-6f);
    o.y = a.y + ny / (dy + 1e-6f);
    ((float2*)xpre)[(size_t)n * 64 + lane] = o;
}

// ---------------------------------------------------------------------------
// BatchNorm stats / finalize, x epilogue, e epilogue
// ---------------------------------------------------------------------------
__global__ void bnstats_k(const float* __restrict__ x, int M,
                          float* __restrict__ sum, float* __restrict__ sumsq)
{
    const int col  = threadIdx.x & 127;
    const int half = threadIdx.x >> 7;
    const int stride = 2 * gridDim.x;
    float s = 0.f, ss = 0.f;
    for (int r = blockIdx.x * 2 + half; r < M; r += stride) {
        float v = x[(size_t)r * 128 + col];
        s += v; ss += v * v;
    }
    __shared__ float Ss[2][128], SSs[2][128];
    Ss[half][col] = s; SSs[half][col] = ss;
    __syncthreads();
    if (half == 0) {
        atomicAdd(&sum[col],   Ss[0][col] + Ss[1][col]);
        atomicAdd(&sumsq[col], SSs[0][col] + SSs[1][col]);
    }
}

__global__ void bnfinal_k(const float* esum, const float* esumsq,
                          const float* xsum, const float* xsumsq,
                          const float* eg, const float* eb,
                          const float* xg, const float* xb,
                          float* esc, float* esh, float* xsc, float* xsh)
{
    int c = threadIdx.x;
    float me = esum[c] * (1.f / EE);
    float ve = esumsq[c] * (1.f / EE) - me * me;
    float se = eg[c] * rsqrtf(ve + 1e-5f);
    esc[c] = se; esh[c] = eb[c] - me * se;
    float mx = xsum[c] * (1.f / NN);
    float vx = xsumsq[c] * (1.f / NN) - mx * mx;
    float sx = xg[c] * rsqrtf(vx + 1e-5f);
    xsc[c] = sx; xsh[c] = xb[c] - mx * sx;
}

__global__ void xpost_k(const float* __restrict__ xpre,
                        const float* __restrict__ hv,
                        const float* __restrict__ xsc,
                        const float* __restrict__ xsh,
                        float* __restrict__ xfin)
{
    int i = blockIdx.x * 1024 + threadIdx.x * 4;
    int c = i & 127;
    float4 v  = *(const float4*)&xpre[i];
    float4 s4 = *(const float4*)&xsc[c];
    float4 h4 = *(const float4*)&xsh[c];
    float4 r4 = *(const float4*)&hv[i];
    float4 o;
    o.x = fmaxf(v.x * s4.x + h4.x, 0.f) + r4.x;
    o.y = fmaxf(v.y * s4.y + h4.y, 0.f) + r4.y;
    o.z = fmaxf(v.z * s4.z + h4.z, 0.f) + r4.z;
    o.w = fmaxf(v.w * s4.w + h4.w, 0.f) + r4.w;
    *(float4*)&xfin[i] = o;
}

// e = relu(e_ij*esc+esh) + he, in place over the he region (d_out)
__global__ void epost_k(const float* __restrict__ e_ij,
                        float* __restrict__ e_out,
                        const float* __restrict__ esc,
                        const float* __restrict__ esh)
{
    int i = blockIdx.x * 1024 + threadIdx.x * 4;
    int c = i & 127;
    float4 ij = *(const float4*)&e_ij[i];
    float4 hv = *(const float4*)&e_out[i];
    float4 s4 = *(const float4*)&esc[c];
    float4 h4 = *(const float4*)&esh[c];
    float4 o;
    o.x = fmaxf(ij.x * s4.x + h4.x, 0.f) + hv.x;
    o.y = fmaxf(ij.y * s4.y + h4.y, 0.f) + hv.y;
    o.z = fmaxf(ij.z * s4.z + h4.z, 0.f) + hv.z;
    o.w = fmaxf(ij.w * s4.w + h4.w, 0.f) + hv.w;
    *(float4*)&e_out[i] = o;
}

// ---------------------------------------------------------------------------
// batch_vec -> starts/counts
// ---------------------------------------------------------------------------
__global__ void meta_k(const int* __restrict__ bvec, int* starts, int* counts)
{
    __shared__ int cnt[BB];
    if (threadIdx.x < BB) cnt[threadIdx.x] = 0;
    __syncthreads();
    for (int i = threadIdx.x; i < NN; i += 256) atomicAdd(&cnt[bvec[i]], 1);
    __syncthreads();
    if (threadIdx.x == 0) {
        int s = 0;
        for (int b = 0; b < BB; ++b) { starts[b] = s; counts[b] = cnt[b]; s += cnt[b]; }
    }
}

// ---------------------------------------------------------------------------
// Flash attention (fp32), per (graph, head, 32-query tile)
// ---------------------------------------------------------------------------
__launch_bounds__(256, 2)
__global__ void attn_k(const float* __restrict__ qkv,
                       const int* __restrict__ starts,
                       const int* __restrict__ counts,
                       float* __restrict__ ctx)
{
    const int b  = blockIdx.x;
    const int h  = blockIdx.y;
    const int qt = blockIdx.z;
    const int cnt = counts[b];
    const int st  = starts[b];
    const int q0  = qt * 32;
    if (q0 >= cnt) return;
    __shared__ float Ks[64][36];
    __shared__ float Vs[64][36];
    __shared__ float Ps[32][68];
    const int tid = threadIdx.x;
    const int qi  = tid >> 3;
    const int sub = tid & 7;
    const int qrow = q0 + qi;
    float4 qv[8];
    if (qrow < cnt) {
        const float* qp = &qkv[(size_t)(st + qrow) * 384 + h * 32];
        #pragma unroll
        for (int c4 = 0; c4 < 8; ++c4) qv[c4] = *(const float4*)&qp[c4 * 4];
    } else {
        #pragma unroll
        for (int c4 = 0; c4 < 8; ++c4) qv[c4] = make_float4(0.f, 0.f, 0.f, 0.f);
    }
    float m = -1e30f, l = 0.f;
    float a0 = 0.f, a1 = 0.f, a2 = 0.f, a3 = 0.f;
    const int nkt = (cnt + 63) >> 6;
    for (int kt = 0; kt < nkt; ++kt) {
        const int kk0 = kt * 64;
        __syncthreads();
        #pragma unroll
        for (int i = 0; i < 8; ++i) {
            int idx = tid + i * 256;
            int r = idx >> 5, c = idx & 31;
            int kg = kk0 + r;
            float kvv = 0.f, vvv = 0.f;
            if (kg < cnt) {
                size_t base = (size_t)(st + kg) * 384 + h * 32;
                kvv = qkv[base + 128 + c];
                vvv = qkv[base + 256 + c];
            }
            Ks[r][c] = kvv;
            Vs[r][c] = vvv;
        }
        __syncthreads();
        float p[8];
        float tmax = -1e30f;
        #pragma unroll
        for (int j2 = 0; j2 < 8; ++j2) {
            int j = sub * 8 + j2;
            float s = 0.f;
            #pragma unroll
            for (int c4 = 0; c4 < 8; ++c4) {
                float4 kv4 = *(const float4*)&Ks[j][c4 * 4];
                s += qv[c4].x * kv4.x + qv[c4].y * kv4.y
                   + qv[c4].z * kv4.z + qv[c4].w * kv4.w;
            }
            s *= 0.17677669529663687f;
            if (kk0 + j >= cnt) s = -1e30f;
            p[j2] = s;
            tmax = fmaxf(tmax, s);
        }
        #pragma unroll
        for (int d = 1; d < 8; d <<= 1) tmax = fmaxf(tmax, __shfl_xor(tmax, d));
        const float mnew = fmaxf(m, tmax);
        const float corr = __expf(m - mnew);
        float tsum = 0.f;
        #pragma unroll
        for (int j2 = 0; j2 < 8; ++j2) {
            float pe = __expf(p[j2] - mnew);
            p[j2] = pe;
            tsum += pe;
        }
        #pragma unroll
        for (int d = 1; d < 8; d <<= 1) tsum += __shfl_xor(tsum, d);
        l = l * corr + tsum;
        m = mnew;
        a0 *= corr; a1 *= corr; a2 *= corr; a3 *= corr;
        #pragma unroll
        for (int j2 = 0; j2 < 8; ++j2) Ps[qi][sub * 8 + j2] = p[j2];
        __syncthreads();
        for (int j = 0; j < 64; ++j) {
            float pj = Ps[qi][j];
            float4 vv = *(const float4*)&Vs[j][sub * 4];
            a0 += pj * vv.x; a1 += pj * vv.y; a2 += pj * vv.z; a3 += pj * vv.w;
        }
    }
    if (qrow < cnt) {
        float inv = 1.f / l;
        float4 o = make_float4(a0 * inv, a1 * inv, a2 * inv, a3 * inv);
        *(float4*)&ctx[(size_t)(st + qrow) * 128 + h * 32 + sub * 4] = o;
    }
}

// ---------------------------------------------------------------------------
// LayerNorm rows of 128
// ---------------------------------------------------------------------------
__global__ void ln_k(const float* __restrict__ x,
                     const float* __restrict__ g,
                     const float* __restrict__ b,
                     float* __restrict__ out, int M)
{
    int row  = blockIdx.x * 4 + (threadIdx.x >> 6);
    int lane = threadIdx.x & 63;
    if (row >= M) return;
    float2 v = *(const float2*)&x[(size_t)row * 128 + lane * 2];
    float s  = v.x + v.y;
    float ss = v.x * v.x + v.y * v.y;
    #pragma unroll
    for (int d = 1; d < 64; d <<= 1) {
        s  += __shfl_xor(s, d);
        ss += __shfl_xor(ss, d);
    }
    float mean = s * (1.f / 128.f);
    float var  = ss * (1.f / 128.f) - mean * mean;
    float inv  = rsqrtf(var + 1e-5f);
    float2 o;
    o.x = (v.x - mean) * inv * g[lane * 2 + 0] + b[lane * 2 + 0];
    o.y = (v.y - mean) * inv * g[lane * 2 + 1] + b[lane * 2 + 1];
    *(float2*)&out[(size_t)row * 128 + lane * 2] = o;
}

extern "C" void kernel_launch(void* const* d_in, const int* in_sizes, int n_in,
                              void* d_out, int out_size, void* d_ws, size_t ws_size,
                              hipStream_t stream) {
    (void)in_sizes; (void)n_in; (void)out_size; (void)ws_size;
    const float* h_v   = (const float*)d_in[0];
    const float* h_e   = (const float*)d_in[1];
    const float* rho_v = (const float*)d_in[2];
    const float* f_k   = (const float*)d_in[3];
    const float* ei_w  = (const float*)d_in[4];
    const float* ei_b  = (const float*)d_in[5];
    const float* ni_w  = (const float*)d_in[6];
    const float* ni_b  = (const float*)d_in[7];
    const float* Aw = (const float*)d_in[8],  *Ab = (const float*)d_in[9];
    const float* Bw = (const float*)d_in[10], *Bb = (const float*)d_in[11];
    const float* Cw = (const float*)d_in[12], *Cb = (const float*)d_in[13];
    const float* Dw = (const float*)d_in[14], *Db = (const float*)d_in[15];
    const float* Ew = (const float*)d_in[16], *Eb = (const float*)d_in[17];
    const float* bnxg = (const float*)d_in[18], *bnxb = (const float*)d_in[19];
    const float* bneg = (const float*)d_in[20], *bneb = (const float*)d_in[21];
    const float* aiw = (const float*)d_in[22], *aib = (const float*)d_in[23];
    const float* aow = (const float*)d_in[24], *aob = (const float*)d_in[25];
    const float* ln1g = (const float*)d_in[26], *ln1b = (const float*)d_in[27];
    const float* ln2g = (const float*)d_in[28], *ln2b = (const float*)d_in[29];
    const float* f1w = (const float*)d_in[30], *f1b = (const float*)d_in[31];
    const float* f2w = (const float*)d_in[32], *f2b = (const float*)d_in[33];
    const float* row1 = (const float*)d_in[34], *rob1 = (const float*)d_in[35];
    const float* row2 = (const float*)d_in[36], *rob2 = (const float*)d_in[37];
    const int* eidx = (const int*)d_in[38];
    const int* bvec = (const int*)d_in[39];
    const int* esrc = eidx;
    const int* edst = eidx + EE;

    float* ws = (float*)d_ws;
    size_t o = 0;
    float* e_ij   = ws + o; o += (size_t)EE * HH;
    float* hv     = ws + o; o += (size_t)NN * HH;
    float* Ax     = ws + o; o += (size_t)NN * HH;
    float* Bx     = ws + o; o += (size_t)NN * HH;
    float* Dx     = ws + o; o += (size_t)NN * HH;
    float* Exm    = ws + o; o += (size_t)NN * HH;
    float* csrf   = ws + o; o += (size_t)NN * HH;   // CSR ints
    float* spare  = ws + o; o += (size_t)NN * HH;   // pads f1 span
    float* x_fin  = ws + o; o += (size_t)NN * HH;
    float* qkvb   = ws + o; o += (size_t)3 * NN * HH;
    float* ctx    = ws + o; o += (size_t)NN * HH;
    float* xd1    = ws + o; o += (size_t)NN * HH;
    float* esum   = ws + o; o += 128;
    float* esumsq = ws + o; o += 128;
    float* xsum   = ws + o; o += 128;
    float* xsumsq = ws + o; o += 128;
    float* esc    = ws + o; o += 128;
    float* esh    = ws + o; o += 128;
    float* xsc    = ws + o; o += 128;
    float* xsh    = ws + o; o += 128;
    int*   meta   = (int*)(ws + o); o += 32;
    (void)spare;
    int* eperm  = (int*)csrf;
    int* deg    = eperm + EE;
    int* offs   = deg + 8192;
    int* cursor = offs + 8193;
    float* xpre = Ax;          // agg writes in place
    float* f1   = Bx;          // N x 512 spans Bx,Dx,Exm,csrf — used after agg/ce
    float* tmp1 = qkvb;
    float* tmp2 = ctx;

    float* out_x     = (float*)d_out;
    float* he        = out_x + (size_t)NN * HH;   // e region; he then e in place
    float* out_delta = he + (size_t)EE * HH;

    hipMemsetAsync(deg, 0, 8192 * sizeof(int), stream);
    hipMemsetAsync(esum, 0, 4 * 128 * sizeof(float), stream);

    dim3 blk(256);
    meta_k<<<1, blk, 0, stream>>>(bvec, meta, meta + BB);
    hist_k<<<256, blk, 0, stream>>>(edst, deg);
    scan_k<<<1, blk, 0, stream>>>(deg, offs, cursor);
    scatter_k<<<512, blk, 0, stream>>>(edst, cursor, eperm);

    // hv = [h_v, rho] @ ni^T
    mgemm_k<X_NODE, EPI_NONE><<<dim3(NN / 64, 1), blk, 0, stream>>>(
        h_v, ni_w, ni_b, hv, 128, 129, 128, nullptr, rho_v, nullptr, nullptr, nullptr);
    // he = [h_e, rho_s, rho_d, fk] @ ei^T
    mgemm_k<X_EDGE, EPI_NONE><<<dim3(EE / 64, 1), blk, 0, stream>>>(
        h_e, ei_w, ei_b, he, 128, 131, 128, nullptr, rho_v, f_k, esrc, edst);
    // A/B/D/E projections
    mgemm_k<X_PLAIN, EPI_NONE><<<dim3(NN / 64, 1), blk, 0, stream>>>(
        hv, Aw, Ab, Ax, 128, 128, 128, nullptr, nullptr, nullptr, nullptr, nullptr);
    mgemm_k<X_PLAIN, EPI_NONE><<<dim3(NN / 64, 1), blk, 0, stream>>>(
        hv, Bw, Bb, Bx, 128, 128, 128, nullptr, nullptr, nullptr, nullptr, nullptr);
    mgemm_k<X_PLAIN, EPI_NONE><<<dim3(NN / 64, 1), blk, 0, stream>>>(
        hv, Dw, Db, Dx, 128, 128, 128, nullptr, nullptr, nullptr, nullptr, nullptr);
    mgemm_k<X_PLAIN, EPI_NONE><<<dim3(NN / 64, 1), blk, 0, stream>>>(
        hv, Ew, Eb, Exm, 128, 128, 128, nullptr, nullptr, nullptr, nullptr, nullptr);
    // Ce + e_ij
    ce_mk<<<dim3(EE / 64), blk, 0, stream>>>(he, Cw, Cb, Dx, Exm, esrc, edst, e_ij);
    // aggregation
    agg_k<<<NN / 4, blk, 0, stream>>>(e_ij, Bx, Ax, esrc, offs, eperm, xpre);
    // BN
    bnstats_k<<<1024, blk, 0, stream>>>(e_ij, EE, esum, esumsq);
    bnstats_k<<<64, blk, 0, stream>>>(xpre, NN, xsum, xsumsq);
    bnfinal_k<<<1, 128, 0, stream>>>(esum, esumsq, xsum, xsumsq,
                                     bneg, bneb, bnxg, bnxb, esc, esh, xsc, xsh);
    xpost_k<<<(NN * HH) / 1024, blk, 0, stream>>>(xpre, hv, xsc, xsh, x_fin);
    // e epilogue (in place over he) then delta readout
    epost_k<<<(EE * HH) / 1024, blk, 0, stream>>>(e_ij, he, esc, esh);
    delta_mk<<<dim3(EE / 64), blk, 0, stream>>>(he, row1, rob1, row2, rob2, out_delta);
    // attention stream
    mgemm_k<X_PLAIN, EPI_NONE><<<dim3(NN / 64, 3), blk, 0, stream>>>(
        x_fin, aiw, aib, qkvb, 128, 128, 384, nullptr, nullptr, nullptr, nullptr, nullptr);
    attn_k<<<dim3(BB, NHEADS, 32), blk, 0, stream>>>(qkvb, meta, meta + BB, ctx);
    mgemm_k<X_PLAIN, EPI_RESID><<<dim3(NN / 64, 1), blk, 0, stream>>>(
        ctx, aow, aob, tmp1, 128, 128, 128, x_fin, nullptr, nullptr, nullptr, nullptr);
    ln_k<<<NN / 4, blk, 0, stream>>>(tmp1, ln1g, ln1b, xd1, NN);
    mgemm_k<X_PLAIN, EPI_RELU><<<dim3(NN / 64, 4), blk, 0, stream>>>(
        xd1, f1w, f1b, f1, 128, 128, 512, nullptr, nullptr, nullptr, nullptr, nullptr);
    mgemm_k<X_PLAIN, EPI_RESID><<<dim3(NN / 64, 1), blk, 0, stream>>>(
        f1, f2w, f2b, tmp2, 512, 512, 128, xd1, nullptr, nullptr, nullptr, nullptr);
    ln_k<<<NN / 4, blk, 0, stream>>>(tmp2, ln2g, ln2b, out_x, NN);
}